// Round 8
// baseline (821.214 us; speedup 1.0000x reference)
//
#include <hip/hip_runtime.h>

// Self-attention, B=4, N=4096, D=256 (single head over full D).
//   Q = x Wq^T + bq ; K,V likewise ; S = Q K^T ; mask==0 -> -inf ;
//   attn = softmax(S/16) ; out = attn V        (fp32 in/out)
// R8: two targets.
//  flash (247us, all pipes <13%): TLP was 2 barrier-groups/CU. Mask ring ->
//   asm regs depth-1 (kills 32KB LDS + its 4-way conflicts); LDS 42.5KB ->
//   3 blocks/CU (launch_bounds(256,3)). vmcnt ladder: [M8][V8] -> vmcnt(8)
//   frees mask -> B2 lgkm -> stage K(t+1) + issue M(t+1) -> vmcnt(16) frees
//   V -> PV -> B1 vmcnt(8) (K in LDS, mask in flight).
//  qkv (~300us hidden behind flash in top-5): 8 serial k-steps x 12
//   divergent loads, ~12 waves/CU. 32-row blocks, grid(512,3)=1536 blocks,
//   launch_bounds(256,4): acc halves -> ~20 waves/CU of latency hiding.
// ws: Qs bf16 8MiB | Kb bf16 8MiB | Vt bf16 8MiB  (= 24MiB, proven)

#define DEV static __device__ __forceinline__

typedef __attribute__((ext_vector_type(8))) short bf8;   // 8 bf16 (4 VGPR)
typedef __attribute__((ext_vector_type(4))) float f4;
typedef const __attribute__((address_space(1))) unsigned int* gp1;
typedef __attribute__((address_space(3))) unsigned int* lp3;

DEV short f2bf(float x) {  // fp32 -> bf16 RNE (inputs finite)
  unsigned u = __builtin_bit_cast(unsigned, x);
  u += 0x7FFFu + ((u >> 16) & 1u);
  return (short)(u >> 16);
}

DEV bf8 cvt8(f4 a, f4 b) {
  bf8 r;
  r[0] = f2bf(a[0]); r[1] = f2bf(a[1]); r[2] = f2bf(a[2]); r[3] = f2bf(a[3]);
  r[4] = f2bf(b[0]); r[5] = f2bf(b[1]); r[6] = f2bf(b[2]); r[7] = f2bf(b[3]);
  return r;
}

DEV bf8 cvtp(const float* p) { return cvt8(*(const f4*)p, *(const f4*)(p + 4)); }

DEV f4 mfma16(bf8 a, bf8 b, f4 c) {
  return __builtin_amdgcn_mfma_f32_16x16x32_bf16(a, b, c, 0, 0, 0);
}

DEV void gl_lds16(const void* g, void* l) {  // async global->LDS, 16B/lane
  __builtin_amdgcn_global_load_lds((gp1)g, (lp3)l, 16, 0, 0);
}

DEV void ld16(bf8& d, const short* p) {  // unsinkable 16B global load
  __asm__ __volatile__("global_load_dwordx4 %0, %1, off" : "=v"(d) : "v"(p));
}
DEV void ld4(int& d, const int* p) {     // unsinkable 4B global load
  __asm__ __volatile__("global_load_dword %0, %1, off" : "=v"(d) : "v"(p));
}

// ---------------- kernel 1: Q,K,V projection (32-row blocks) --------------
// grid (512, 3): x=row-block of 32, y=which (0=Q,1=K,2=V). TLP-first:
// small acc (32 VGPR) -> ~5 waves/EU hides the divergent-load convoy.
__launch_bounds__(256, 4)
__global__ void qkv(const float* __restrict__ x, const float* __restrict__ Wq,
                    const float* __restrict__ Wk, const float* __restrict__ Wv,
                    const float* __restrict__ bq, const float* __restrict__ bk,
                    const float* __restrict__ bv, short* __restrict__ Qs,
                    short* __restrict__ Kb, short* __restrict__ Vt) {
  __shared__ short Vlds[256 * 36];  // V transpose staging (32 rows)
  const int which = blockIdx.y;
  const int m0 = blockIdx.x * 32;
  const int tid = threadIdx.x;
  const int w = tid >> 6, lane = tid & 63, quad = lane >> 4, c = lane & 15;
  const float* W = (which == 0) ? Wq : (which == 1) ? Wk : Wv;
  const float* bias = (which == 0) ? bq : (which == 1) ? bk : bv;

  f4 acc[2][4];
  const f4 z = {0.f, 0.f, 0.f, 0.f};
#pragma unroll
  for (int i = 0; i < 2; i++)
#pragma unroll
    for (int j = 0; j < 4; j++) acc[i][j] = z;

#pragma unroll
  for (int ks = 0; ks < 8; ks++) {
    bf8 a[2], b[4];
#pragma unroll
    for (int ms = 0; ms < 2; ms++)  // A[m=lane&15][k=quad*8+j]
      a[ms] = cvtp(x + (m0 + ms * 16 + c) * 256 + ks * 32 + quad * 8);
#pragma unroll
    for (int e = 0; e < 4; e++)     // B[k=d][n=e] = W[e][d] (row-major W)
      b[e] = cvtp(W + ((w * 4 + e) * 16 + c) * 256 + ks * 32 + quad * 8);
#pragma unroll
    for (int ms = 0; ms < 2; ms++)
#pragma unroll
      for (int e = 0; e < 4; e++) acc[ms][e] = mfma16(a[ms], b[e], acc[ms][e]);
  }

  float bb[4];
#pragma unroll
  for (int e = 0; e < 4; e++) bb[e] = bias[(w * 4 + e) * 16 + c];
  const float sc = (which == 0) ? 0.09016844005556021f : 1.0f;  // log2e/16

  if (which < 2) {
    short* dst = (which == 0) ? Qs : Kb;
#pragma unroll
    for (int ms = 0; ms < 2; ms++)
#pragma unroll
      for (int e = 0; e < 4; e++)
#pragma unroll
        for (int r = 0; r < 4; r++)  // C/D: col=lane&15, row=quad*4+reg
          dst[(m0 + ms * 16 + quad * 4 + r) * 256 + (w * 4 + e) * 16 + c] =
              f2bf((acc[ms][e][r] + bb[e]) * sc);
  } else {
    // V: transpose through LDS, emit into tiled Vt [tt][256 d][64 n]
#pragma unroll
    for (int ms = 0; ms < 2; ms++)
#pragma unroll
      for (int e = 0; e < 4; e++)
#pragma unroll
        for (int r = 0; r < 4; r++)
          Vlds[((w * 4 + e) * 16 + c) * 36 + ms * 16 + quad * 4 + r] =
              f2bf(acc[ms][e][r] + bb[e]);
    __syncthreads();
    const int tt = m0 >> 6, half = m0 & 32;
#pragma unroll
    for (int j = 0; j < 4; j++) {
      int flat = j * 2048 + tid * 8;        // 256 d x 32 n
      int d = flat >> 5, n = flat & 31;
      *(bf8*)(Vt + tt * 16384 + d * 64 + half + n) =
          *(const bf8*)&Vlds[d * 36 + n];
    }
  }
}

// ---------------- kernel 2: flash attention ----------------
// 512 WGs, 3 blocks/CU. batch = bx&3 (per-XCD batch affinity). Per tile:
//  issue V(t) regs -> QK (swizzled Klds ds_reads) -> vmcnt(8) [mask(t)
//  ready, V stays] -> P=exp2(masked S) -> B2(lgkm+barrier) -> stage K(t+1)
//  gl_lds + issue M(t+1) regs -> vmcnt(16) [V ready] -> PV ->
//  B1(vmcnt(8)+barrier) [K(t+1) in LDS; M(t+1) still flying].
__launch_bounds__(256, 3)
__global__ void flash(const short* __restrict__ Qs, const short* __restrict__ Kb,
                      const short* __restrict__ Vt, const int* __restrict__ mask,
                      float* __restrict__ out) {
  __shared__ short Klds[16384];       // K tile 64x256, chunk-XOR-swizzled
  __shared__ short Plds[2][32 * 76];  // P dbuf, stride 76 (conflict-free)
  const int bx = blockIdx.x;
  const int batch = bx & 3;
  const int q0 = (bx >> 2) * 32;
  const int tid = threadIdx.x;
  const int w = tid >> 6, lane = tid & 63, quad = lane >> 4, c = lane & 15;

  const short* kb = Kb + batch * 4096 * 256;
  const short* vb = Vt + batch * 1048576;
  const int* mb = mask + batch * 16777216;

  const int krow = tid >> 5;   // K staging: row-in-8-row-line (0..7)
  const int kch = tid & 31;    // LDS chunk this thread fills

  // ---- prologue: issue mask(0) regs, stage K(0), load Q ----
  int mc[8], mn[8];
#pragma unroll
  for (int ms = 0; ms < 2; ms++)
#pragma unroll
    for (int r = 0; r < 4; r++)
      ld4(mc[ms * 4 + r], mb + (q0 + ms * 16 + quad * 4 + r) * 4096 + w * 16 + c);
#pragma unroll
  for (int l = 0; l < 8; l++) {
    const int row = l * 8 + krow;
    const int chg = (kch & 16) | ((kch ^ row) & 15);  // involutive swizzle
    gl_lds16(kb + row * 256 + chg * 8, &Klds[l * 2048 + tid * 8]);
  }
  bf8 aq[2][8];
  const short* qb = Qs + (batch * 4096 + q0) * 256;
#pragma unroll
  for (int ms = 0; ms < 2; ms++)
#pragma unroll
    for (int ks = 0; ks < 8; ks++)
      aq[ms][ks] = *(const bf8*)(qb + (ms * 16 + c) * 256 + ks * 32 + quad * 8);

  const f4 z = {0.f, 0.f, 0.f, 0.f};
  f4 accO[2][4], lacc[2];
#pragma unroll
  for (int ms = 0; ms < 2; ms++) {
    lacc[ms] = z;
#pragma unroll
    for (int ds = 0; ds < 4; ds++) accO[ms][ds] = z;
  }
  const bf8 ONES = {0x3F80, 0x3F80, 0x3F80, 0x3F80, 0x3F80, 0x3F80, 0x3F80, 0x3F80};

  // drain prologue (M(0), K(0), Q all resident)
  __asm__ __volatile__("s_waitcnt vmcnt(0)\ns_barrier"
      : "+v"(mc[0]), "+v"(mc[1]), "+v"(mc[2]), "+v"(mc[3]),
        "+v"(mc[4]), "+v"(mc[5]), "+v"(mc[6]), "+v"(mc[7]) :: "memory");

  for (int t = 0; t < 64; t++) {
    // ---- issue V(t) regs (consumed after B2, ~2 sections later) ----
    bf8 vc[2][4];
#pragma unroll
    for (int k2 = 0; k2 < 2; k2++)
#pragma unroll
      for (int ds = 0; ds < 4; ds++)
        ld16(vc[k2][ds], vb + t * 16384 + (w * 64 + ds * 16 + c) * 64 +
                         k2 * 32 + quad * 8);

    // ---- S = Q' K^T from swizzled LDS (wave strip: rows w*16+c) ----
    f4 s[2];
#pragma unroll
    for (int ms = 0; ms < 2; ms++) s[ms] = z;
#pragma unroll
    for (int ks = 0; ks < 8; ks++) {
      const int ch = ks * 4 + quad;
      const int sw = (ch & 16) | ((ch ^ c) & 15);
      const bf8 kf = *(const bf8*)&Klds[(w * 16 + c) * 256 + sw * 8];
#pragma unroll
      for (int ms = 0; ms < 2; ms++) s[ms] = mfma16(aq[ms][ks], kf, s[ms]);
    }

    // ---- mask(t) ready (queue: [M(t)8][V(t)8] -> keep V flying) ----
    __asm__ __volatile__("s_waitcnt vmcnt(8)"
        : "+v"(mc[0]), "+v"(mc[1]), "+v"(mc[2]), "+v"(mc[3]),
          "+v"(mc[4]), "+v"(mc[5]), "+v"(mc[6]), "+v"(mc[7]) :: "memory");

    // ---- P = exp2(masked S) -> LDS (C-layout -> A-layout) ----
    short* pw = &Plds[t & 1][0];
#pragma unroll
    for (int ms = 0; ms < 2; ms++)
#pragma unroll
      for (int r = 0; r < 4; r++) {
        float sv = (mc[ms * 4 + r] != 0) ? s[ms][r] : -INFINITY;
        pw[(ms * 16 + quad * 4 + r) * 76 + w * 16 + c] =
            f2bf(__builtin_amdgcn_exp2f(sv));
      }
    // B2: P visible; VM queue untouched
    __asm__ __volatile__("s_waitcnt lgkmcnt(0)\ns_barrier" ::: "memory");

    // ---- stage K(t+1) (LDS) + issue mask(t+1) (regs) ----
    const int tk = (t < 63) ? t + 1 : 63;
    const short* kbt = kb + tk * 16384;
#pragma unroll
    for (int l = 0; l < 8; l++) {
      const int row = l * 8 + krow;
      const int chg = (kch & 16) | ((kch ^ row) & 15);
      gl_lds16(kbt + row * 256 + chg * 8, &Klds[l * 2048 + tid * 8]);
    }
#pragma unroll
    for (int ms = 0; ms < 2; ms++)
#pragma unroll
      for (int r = 0; r < 4; r++)
        ld4(mn[ms * 4 + r],
            mb + (q0 + ms * 16 + quad * 4 + r) * 4096 + tk * 64 + w * 16 + c);

    // ---- V(t) ready (drain V; K(t+1)8 + M(t+1)8 stay in flight) ----
    __asm__ __volatile__("s_waitcnt vmcnt(16)"
        : "+v"(vc[0][0]), "+v"(vc[0][1]), "+v"(vc[0][2]), "+v"(vc[0][3]),
          "+v"(vc[1][0]), "+v"(vc[1][1]), "+v"(vc[1][2]), "+v"(vc[1][3])
        :: "memory");

    // ---- O += P V ; row-sum via ones-frag MFMA ----
#pragma unroll
    for (int k2 = 0; k2 < 2; k2++) {
      bf8 ap[2];
#pragma unroll
      for (int ms = 0; ms < 2; ms++)  // A[m=lane&15][k=quad*8+j]
        ap[ms] = *(const bf8*)&pw[(ms * 16 + c) * 76 + k2 * 32 + quad * 8];
#pragma unroll
      for (int ms = 0; ms < 2; ms++) {
        lacc[ms] = mfma16(ap[ms], ONES, lacc[ms]);
#pragma unroll
        for (int ds = 0; ds < 4; ds++)
          accO[ms][ds] = mfma16(ap[ms], vc[k2][ds], accO[ms][ds]);
      }
    }

    // B1: K(t+1) arrived in LDS (mask(t+1) keeps flying); Klds WAR safe
    __asm__ __volatile__("s_waitcnt vmcnt(8)\ns_barrier" ::: "memory");
#pragma unroll
    for (int i2 = 0; i2 < 8; i2++) mc[i2] = mn[i2];
  }

  // ---- epilogue: O / l ----
  float* ob = out + (batch * 4096 + q0) * 256;
#pragma unroll
  for (int ms = 0; ms < 2; ms++) {
    f4 rl;
#pragma unroll
    for (int r = 0; r < 4; r++) rl[r] = __builtin_amdgcn_rcpf(lacc[ms][r]);
#pragma unroll
    for (int ds = 0; ds < 4; ds++)
#pragma unroll
      for (int r = 0; r < 4; r++)
        ob[(ms * 16 + quad * 4 + r) * 256 + w * 64 + ds * 16 + c] =
            accO[ms][ds][r] * rl[r];
  }
}

extern "C" void kernel_launch(void* const* d_in, const int* in_sizes, int n_in,
                              void* d_out, int out_size, void* d_ws, size_t ws_size,
                              hipStream_t stream) {
  const float* x = (const float*)d_in[0];
  const int* mask = (const int*)d_in[1];
  const float* Wq = (const float*)d_in[2];
  const float* bq = (const float*)d_in[3];
  const float* Wk = (const float*)d_in[4];
  const float* bk = (const float*)d_in[5];
  const float* Wv = (const float*)d_in[6];
  const float* bv = (const float*)d_in[7];
  float* out = (float*)d_out;

  char* ws = (char*)d_ws;  // 24 MiB
  short* Qs = (short*)ws;
  short* Kb = (short*)(ws + (8u << 20));
  short* Vt = (short*)(ws + (16u << 20));

  qkv<<<dim3(512, 3), 256, 0, stream>>>(x, Wq, Wk, Wv, bq, bk, bv, Qs, Kb, Vt);
  flash<<<512, 256, 0, stream>>>(Qs, Kb, Vt, mask, out);
}

// Round 9
// 538.736 us; speedup vs baseline: 1.5243x; 1.5243x over previous
//
#include <hip/hip_runtime.h>

// Self-attention, B=4, N=4096, D=256 (single head over full D).
//   Q = x Wq^T + bq ; K,V likewise ; S = Q K^T ; mask==0 -> -inf ;
//   attn = softmax(S/16) ; out = attn V        (fp32 in/out)
// R9: R8's launch_bounds(256,3) + asm-pinned regs => spill catastrophe
//     (WRITE 16->60MB scratch). Revert flash to R7 verbatim (247us best).
//     Attack qkv (~300us, co-equal): W pre-packed to bf16 frag-order (pack
//     kernel) -> B-frag = 1 coalesced 16B/lane load; x-tile staged once per
//     block via global_load_lds (swizzled, 2-way-free ds_read); 32-row
//     blocks, grid(512,3), bounds(256,3) with ~90 live VGPR (no spill).
// ws: Qs bf16 8MiB | Kb bf16 8MiB | Vt bf16 8MiB | Wp 384KiB

#define DEV static __device__ __forceinline__

typedef __attribute__((ext_vector_type(8))) short bf8;   // 8 bf16 (4 VGPR)
typedef __attribute__((ext_vector_type(4))) float f4;
typedef const __attribute__((address_space(1))) unsigned int* gp1;
typedef __attribute__((address_space(3))) unsigned int* lp3;

DEV short f2bf(float x) {  // fp32 -> bf16 RNE (inputs finite)
  unsigned u = __builtin_bit_cast(unsigned, x);
  u += 0x7FFFu + ((u >> 16) & 1u);
  return (short)(u >> 16);
}

DEV bf8 cvt8(f4 a, f4 b) {
  bf8 r;
  r[0] = f2bf(a[0]); r[1] = f2bf(a[1]); r[2] = f2bf(a[2]); r[3] = f2bf(a[3]);
  r[4] = f2bf(b[0]); r[5] = f2bf(b[1]); r[6] = f2bf(b[2]); r[7] = f2bf(b[3]);
  return r;
}

DEV bf8 cvtp(const float* p) { return cvt8(*(const f4*)p, *(const f4*)(p + 4)); }

DEV f4 mfma16(bf8 a, bf8 b, f4 c) {
  return __builtin_amdgcn_mfma_f32_16x16x32_bf16(a, b, c, 0, 0, 0);
}

DEV void gl_lds16(const void* g, void* l) {  // async global->LDS, 16B/lane
  __builtin_amdgcn_global_load_lds((gp1)g, (lp3)l, 16, 0, 0);
}

DEV void ld16(bf8& d, const short* p) {  // unsinkable 16B global load
  __asm__ __volatile__("global_load_dwordx4 %0, %1, off" : "=v"(d) : "v"(p));
}

// ---------------- kernel 0: pack W -> bf16 fragment-order ----------------
// Wp chunk = ((which*4 + w)*4 + e)*8 + ks ; element [lane][j] =
// W_which[(w*4+e)*16 + (lane&15)][ks*32 + (lane>>4)*8 + j].
// 96 blocks x 256 thr = 384 chunks x 64 lanes.
__global__ void pack(const float* __restrict__ Wq, const float* __restrict__ Wk,
                     const float* __restrict__ Wv, short* __restrict__ Wp) {
  const int ch = blockIdx.x * 4 + (threadIdx.x >> 6);
  const int lane = threadIdx.x & 63;
  const int which = ch >> 7, rem = ch & 127;
  const int w = rem >> 5, e = (rem >> 3) & 3, ks = rem & 7;
  const float* W = (which == 0) ? Wq : (which == 1) ? Wk : Wv;
  bf8 v = cvtp(W + ((w * 4 + e) * 16 + (lane & 15)) * 256 + ks * 32 +
               (lane >> 4) * 8);
  *(bf8*)(Wp + ch * 512 + lane * 8) = v;
}

// ---------------- kernel 1: Q,K,V projection ----------------
// grid (512, 3): x=row-block of 32, y=which (0=Q,1=K,2=V). x-tile staged
// once via gl_lds (fp32, XOR-swizzled 16B chunks); A-frags = 2 ds_read_b128
// + cvt; B-frags = coalesced 16B/lane from Wp. No divergent global loads.
__launch_bounds__(256, 3)
__global__ void qkv(const float* __restrict__ x, const short* __restrict__ Wp,
                    const float* __restrict__ bq, const float* __restrict__ bk,
                    const float* __restrict__ bv, short* __restrict__ Qs,
                    short* __restrict__ Kb, short* __restrict__ Vt) {
  __shared__ float Xf[32 * 256];    // x tile, swizzled, 32KB
  __shared__ short Vlds[256 * 36];  // V transpose staging (which==2 only)
  const int which = blockIdx.y;
  const int m0 = blockIdx.x * 32;
  const int tid = threadIdx.x;
  const int w = tid >> 6, lane = tid & 63, quad = lane >> 4, c = lane & 15;
  const float* bias = (which == 0) ? bq : (which == 1) ? bk : bv;

  // ---- stage x tile: 8 issues x 4KB; row = l*4 + tid>>6, slot = tid&63 ----
#pragma unroll
  for (int l = 0; l < 8; l++) {
    const int row = l * 4 + (tid >> 6);
    const int kch = tid & 63;
    const int chg = (kch & 48) | ((kch ^ (row & 15)) & 15);  // involutive
    gl_lds16(x + (m0 + row) * 256 + chg * 4, &Xf[(l * 256 + tid) * 4]);
  }

  float bb[4];
#pragma unroll
  for (int e = 0; e < 4; e++) bb[e] = bias[(w * 4 + e) * 16 + c];

  f4 acc[2][4];
  const f4 z = {0.f, 0.f, 0.f, 0.f};
#pragma unroll
  for (int i = 0; i < 2; i++)
#pragma unroll
    for (int j = 0; j < 4; j++) acc[i][j] = z;

  __asm__ __volatile__("s_waitcnt vmcnt(0)\ns_barrier" ::: "memory");

  const short* wpb = Wp + (which * 4 + w) * 4 * 8 * 512;
#pragma unroll
  for (int ks = 0; ks < 8; ks++) {
    bf8 a[2], b[4];
#pragma unroll
    for (int ms = 0; ms < 2; ms++) {  // A[m=lane&15][k=quad*8+j]
      const int m = ms * 16 + c;
      const int ch0 = ks * 8 + quad * 2;
      const int sw0 = (ch0 & 48) | ((ch0 ^ c) & 15);
      const int sw1 = ((ch0 + 1) & 48) | (((ch0 + 1) ^ c) & 15);
      f4 f0 = *(const f4*)&Xf[m * 256 + sw0 * 4];
      f4 f1 = *(const f4*)&Xf[m * 256 + sw1 * 4];
      a[ms] = cvt8(f0, f1);
    }
#pragma unroll
    for (int e = 0; e < 4; e++)
      b[e] = *(const bf8*)(wpb + (e * 8 + ks) * 512 + lane * 8);
#pragma unroll
    for (int ms = 0; ms < 2; ms++)
#pragma unroll
      for (int e = 0; e < 4; e++) acc[ms][e] = mfma16(a[ms], b[e], acc[ms][e]);
  }

  const float sc = (which == 0) ? 0.09016844005556021f : 1.0f;  // log2e/16

  if (which < 2) {
    short* dst = (which == 0) ? Qs : Kb;
#pragma unroll
    for (int ms = 0; ms < 2; ms++)
#pragma unroll
      for (int e = 0; e < 4; e++)
#pragma unroll
        for (int r = 0; r < 4; r++)  // C/D: col=lane&15, row=quad*4+reg
          dst[(m0 + ms * 16 + quad * 4 + r) * 256 + (w * 4 + e) * 16 + c] =
              f2bf((acc[ms][e][r] + bb[e]) * sc);
  } else {
    // V: transpose through LDS, emit into tiled Vt [tt][256 d][64 n]
#pragma unroll
    for (int ms = 0; ms < 2; ms++)
#pragma unroll
      for (int e = 0; e < 4; e++)
#pragma unroll
        for (int r = 0; r < 4; r++)
          Vlds[((w * 4 + e) * 16 + c) * 36 + ms * 16 + quad * 4 + r] =
              f2bf(acc[ms][e][r] + bb[e]);
    __syncthreads();
    const int tt = m0 >> 6, half = m0 & 32;
#pragma unroll
    for (int j = 0; j < 4; j++) {
      int flat = j * 2048 + tid * 8;        // 256 d x 32 n
      int d = flat >> 5, n = flat & 31;
      *(bf8*)(Vt + tt * 16384 + d * 64 + half + n) =
          *(const bf8*)&Vlds[d * 36 + n];
    }
  }
}

// ---------------- kernel 2: flash attention (R7 verbatim) ----------------
// 512 WGs (2/CU). batch = bx&3 (per-XCD batch affinity). Per tile:
//  [K(t),m(t) in LDS]  issue V(t) regs -> QK(frag ds_reads, swizzled)
//  -> P=exp2(masked S) -> B2(lgkm+barrier) -> stage K(t+1), m(t+4)
//  -> vmcnt(10) [V ready] -> PV -> B1(vmcnt(2)+barrier) [K(t+1) ready].
__launch_bounds__(256, 2)
__global__ void flash(const short* __restrict__ Qs, const short* __restrict__ Kb,
                      const short* __restrict__ Vt, const int* __restrict__ mask,
                      float* __restrict__ out) {
  __shared__ short Klds[16384];    // K tile 64x256, chunk-XOR-swizzled, 32KB
  __shared__ int Mlds[4][2048];    // mask ring: 4 tiles x 32row x 64col, 32KB
  __shared__ short Plds[2][32 * 76];  // P dbuf, stride 76 (conflict-free)
  const int bx = blockIdx.x;
  const int batch = bx & 3;
  const int q0 = (bx >> 2) * 32;
  const int tid = threadIdx.x;
  const int w = tid >> 6, lane = tid & 63, quad = lane >> 4, c = lane & 15;

  const short* kb = Kb + batch * 4096 * 256;
  const short* vb = Vt + batch * 1048576;
  const int* mb = mask + batch * 16777216;

  const int krow = tid >> 5;            // row-in-8-row-line (0..7)
  const int kch = tid & 31;             // LDS chunk this thread fills
  const int mrow = tid >> 4, mco = (tid & 15) * 4;

  // ---- prologue: stage K(0) then mask(0..3) ----
#pragma unroll
  for (int l = 0; l < 8; l++) {
    const int row = l * 8 + krow;
    const int chg = (kch & 16) | ((kch ^ row) & 15);  // involutive swizzle
    gl_lds16(kb + row * 256 + chg * 8, &Klds[l * 2048 + tid * 8]);
  }
#pragma unroll
  for (int tt = 0; tt < 4; tt++)
#pragma unroll
    for (int l2 = 0; l2 < 2; l2++)
      gl_lds16(mb + (q0 + l2 * 16 + mrow) * 4096 + tt * 64 + mco,
               &Mlds[tt][l2 * 1024 + tid * 4]);

  bf8 aq[2][8];
  const short* qb = Qs + (batch * 4096 + q0) * 256;
#pragma unroll
  for (int ms = 0; ms < 2; ms++)
#pragma unroll
    for (int ks = 0; ks < 8; ks++)
      aq[ms][ks] = *(const bf8*)(qb + (ms * 16 + c) * 256 + ks * 32 + quad * 8);

  const f4 z = {0.f, 0.f, 0.f, 0.f};
  f4 accO[2][4], lacc[2];
#pragma unroll
  for (int ms = 0; ms < 2; ms++) {
    lacc[ms] = z;
#pragma unroll
    for (int ds = 0; ds < 4; ds++) accO[ms][ds] = z;
  }
  const bf8 ONES = {0x3F80, 0x3F80, 0x3F80, 0x3F80, 0x3F80, 0x3F80, 0x3F80, 0x3F80};

  // K(0)+mask(0) arrived; masks(1..3) may still fly (3x2 issues = 6)
  __asm__ __volatile__("s_waitcnt vmcnt(6)\ns_barrier" ::: "memory");

  for (int t = 0; t < 64; t++) {
    // ---- issue V(t) into regs (consumed after B2, ~2 barriers later) ----
    bf8 vc[2][4];
#pragma unroll
    for (int k2 = 0; k2 < 2; k2++)
#pragma unroll
      for (int ds = 0; ds < 4; ds++)
        ld16(vc[k2][ds], vb + t * 16384 + (w * 64 + ds * 16 + c) * 64 +
                         k2 * 32 + quad * 8);

    // ---- S = Q' K^T from swizzled LDS (wave strip: rows w*16+c) ----
    f4 s[2];
#pragma unroll
    for (int ms = 0; ms < 2; ms++) s[ms] = z;
#pragma unroll
    for (int ks = 0; ks < 8; ks++) {
      const int ch = ks * 4 + quad;
      const int sw = (ch & 16) | ((ch ^ c) & 15);
      const bf8 kf = *(const bf8*)&Klds[(w * 16 + c) * 256 + sw * 8];
#pragma unroll
      for (int ms = 0; ms < 2; ms++) s[ms] = mfma16(aq[ms][ks], kf, s[ms]);
    }

    // ---- P = exp2(masked S) -> LDS (C-layout -> A-layout) ----
    const int* mrow_p = &Mlds[t & 3][w * 16 + c];
    short* pw = &Plds[t & 1][0];
#pragma unroll
    for (int ms = 0; ms < 2; ms++)
#pragma unroll
      for (int r = 0; r < 4; r++) {
        const int mv = mrow_p[(ms * 16 + quad * 4 + r) * 64];
        float sv = (mv != 0) ? s[ms][r] : -INFINITY;
        pw[(ms * 16 + quad * 4 + r) * 76 + w * 16 + c] =
            f2bf(__builtin_amdgcn_exp2f(sv));
      }
    // B2: P (and this tile's LDS reads) visible; VM queue untouched
    __asm__ __volatile__("s_waitcnt lgkmcnt(0)\ns_barrier" ::: "memory");

    // ---- stage K(t+1) + mask(t+4) (async, consumed next iters) ----
    const int tk = (t < 63) ? t + 1 : 63;
    const short* kbt = kb + tk * 16384;
#pragma unroll
    for (int l = 0; l < 8; l++) {
      const int row = l * 8 + krow;
      const int chg = (kch & 16) | ((kch ^ row) & 15);
      gl_lds16(kbt + row * 256 + chg * 8, &Klds[l * 2048 + tid * 8]);
    }
    const int tm = (t + 4 < 64) ? t + 4 : 63;
#pragma unroll
    for (int l2 = 0; l2 < 2; l2++)
      gl_lds16(mb + (q0 + l2 * 16 + mrow) * 4096 + tm * 64 + mco,
               &Mlds[tm & 3][l2 * 1024 + tid * 4]);

    // ---- V(t) ready: drain everything older (K(t+1)8 + m2 stay) ----
    __asm__ __volatile__("s_waitcnt vmcnt(10)"
        : "+v"(vc[0][0]), "+v"(vc[0][1]), "+v"(vc[0][2]), "+v"(vc[0][3]),
          "+v"(vc[1][0]), "+v"(vc[1][1]), "+v"(vc[1][2]), "+v"(vc[1][3])
        :: "memory");

    // ---- O += P V ; row-sum via ones-frag MFMA ----
#pragma unroll
    for (int k2 = 0; k2 < 2; k2++) {
      bf8 ap[2];
#pragma unroll
      for (int ms = 0; ms < 2; ms++)  // A[m=lane&15][k=quad*8+j]
        ap[ms] = *(const bf8*)&pw[(ms * 16 + c) * 76 + k2 * 32 + quad * 8];
#pragma unroll
      for (int ms = 0; ms < 2; ms++) {
        lacc[ms] = mfma16(ap[ms], ONES, lacc[ms]);
#pragma unroll
        for (int ds = 0; ds < 4; ds++)
          accO[ms][ds] = mfma16(ap[ms], vc[k2][ds], accO[ms][ds]);
      }
    }

    // B1: K(t+1) arrived (leave mask(t+4) in flight); WAR safe for Klds
    __asm__ __volatile__("s_waitcnt vmcnt(2)\ns_barrier" ::: "memory");
  }

  // ---- epilogue: O / l ----
  float* ob = out + (batch * 4096 + q0) * 256;
#pragma unroll
  for (int ms = 0; ms < 2; ms++) {
    f4 rl;
#pragma unroll
    for (int r = 0; r < 4; r++) rl[r] = __builtin_amdgcn_rcpf(lacc[ms][r]);
#pragma unroll
    for (int ds = 0; ds < 4; ds++)
#pragma unroll
      for (int r = 0; r < 4; r++)
        ob[(ms * 16 + quad * 4 + r) * 256 + w * 64 + ds * 16 + c] =
            accO[ms][ds][r] * rl[r];
  }
}

extern "C" void kernel_launch(void* const* d_in, const int* in_sizes, int n_in,
                              void* d_out, int out_size, void* d_ws, size_t ws_size,
                              hipStream_t stream) {
  const float* x = (const float*)d_in[0];
  const int* mask = (const int*)d_in[1];
  const float* Wq = (const float*)d_in[2];
  const float* bq = (const float*)d_in[3];
  const float* Wk = (const float*)d_in[4];
  const float* bk = (const float*)d_in[5];
  const float* Wv = (const float*)d_in[6];
  const float* bv = (const float*)d_in[7];
  float* out = (float*)d_out;

  char* ws = (char*)d_ws;  // 24 MiB + 384 KiB
  short* Qs = (short*)ws;
  short* Kb = (short*)(ws + (8u << 20));
  short* Vt = (short*)(ws + (16u << 20));
  short* Wp = (short*)(ws + (24u << 20));

  pack<<<96, 256, 0, stream>>>(Wq, Wk, Wv, Wp);
  qkv<<<dim3(512, 3), 256, 0, stream>>>(x, Wp, bq, bk, bv, Qs, Kb, Vt);
  flash<<<512, 256, 0, stream>>>(Qs, Kb, Vt, mask, out);
}

// Round 10
// 524.503 us; speedup vs baseline: 1.5657x; 1.0271x over previous
//
#include <hip/hip_runtime.h>

// Self-attention, B=4, N=4096, D=256 (single head over full D).
//   Q = x Wq^T + bq ; K,V likewise ; S = Q K^T ; mask==0 -> -inf ;
//   attn = softmax(S/16) ; out = attn V        (fp32 in/out)
// R10: non-flash gap (~290us) is constant across ALL kernel sets => harness
//   restore/poison floor; flash (248us) is the only lever. Flash was pinned
//   because the loop still had compiler global loads (Q frags) -> compiler
//   inserts its own vmcnt waits that ignore my asm/gl_lds queue. Now:
//   - ZERO compiler VM ops in the loop (Q via asm prologue, out at end)
//   - Klds double-buffered: K(t+1) staged at tile TOP (~1400cyc cover)
//   - Mlds deleted: mask in register dbuf depth-2 (M(t+2) post-B2), FIFO
//     drain proven by vmcnt(16) before PV; 2-phase manual unroll (no
//     dynamic reg indexing, no copies of in-flight regs)
//   - waits: vmcnt(24) order-only, vmcnt(16) V-ready, B1 vmcnt(8) K-ready
// ws: Qs bf16 8MiB | Kb bf16 8MiB | Vt bf16 8MiB | Wp 384KiB

#define DEV static __device__ __forceinline__

typedef __attribute__((ext_vector_type(8))) short bf8;   // 8 bf16 (4 VGPR)
typedef __attribute__((ext_vector_type(4))) float f4;
typedef const __attribute__((address_space(1))) unsigned int* gp1;
typedef __attribute__((address_space(3))) unsigned int* lp3;

DEV short f2bf(float x) {  // fp32 -> bf16 RNE (inputs finite)
  unsigned u = __builtin_bit_cast(unsigned, x);
  u += 0x7FFFu + ((u >> 16) & 1u);
  return (short)(u >> 16);
}

DEV bf8 cvt8(f4 a, f4 b) {
  bf8 r;
  r[0] = f2bf(a[0]); r[1] = f2bf(a[1]); r[2] = f2bf(a[2]); r[3] = f2bf(a[3]);
  r[4] = f2bf(b[0]); r[5] = f2bf(b[1]); r[6] = f2bf(b[2]); r[7] = f2bf(b[3]);
  return r;
}

DEV bf8 cvtp(const float* p) { return cvt8(*(const f4*)p, *(const f4*)(p + 4)); }

DEV f4 mfma16(bf8 a, bf8 b, f4 c) {
  return __builtin_amdgcn_mfma_f32_16x16x32_bf16(a, b, c, 0, 0, 0);
}

DEV void gl_lds16(const void* g, void* l) {  // async global->LDS, 16B/lane
  __builtin_amdgcn_global_load_lds((gp1)g, (lp3)l, 16, 0, 0);
}

DEV void ld16(bf8& d, const short* p) {  // unsinkable 16B global load
  __asm__ __volatile__("global_load_dwordx4 %0, %1, off" : "=v"(d) : "v"(p));
}
DEV void ld4(int& d, const int* p) {     // unsinkable 4B global load
  __asm__ __volatile__("global_load_dword %0, %1, off" : "=v"(d) : "v"(p));
}

// ---------------- kernel 0: pack W -> bf16 fragment-order (R9) ------------
__global__ void pack(const float* __restrict__ Wq, const float* __restrict__ Wk,
                     const float* __restrict__ Wv, short* __restrict__ Wp) {
  const int ch = blockIdx.x * 4 + (threadIdx.x >> 6);
  const int lane = threadIdx.x & 63;
  const int which = ch >> 7, rem = ch & 127;
  const int w = rem >> 5, e = (rem >> 3) & 3, ks = rem & 7;
  const float* W = (which == 0) ? Wq : (which == 1) ? Wk : Wv;
  bf8 v = cvtp(W + ((w * 4 + e) * 16 + (lane & 15)) * 256 + ks * 32 +
               (lane >> 4) * 8);
  *(bf8*)(Wp + ch * 512 + lane * 8) = v;
}

// ---------------- kernel 1: Q,K,V projection (R9) -------------------------
__launch_bounds__(256, 3)
__global__ void qkv(const float* __restrict__ x, const short* __restrict__ Wp,
                    const float* __restrict__ bq, const float* __restrict__ bk,
                    const float* __restrict__ bv, short* __restrict__ Qs,
                    short* __restrict__ Kb, short* __restrict__ Vt) {
  __shared__ float Xf[32 * 256];    // x tile, swizzled, 32KB
  __shared__ short Vlds[256 * 36];  // V transpose staging (which==2 only)
  const int which = blockIdx.y;
  const int m0 = blockIdx.x * 32;
  const int tid = threadIdx.x;
  const int w = tid >> 6, lane = tid & 63, quad = lane >> 4, c = lane & 15;
  const float* bias = (which == 0) ? bq : (which == 1) ? bk : bv;

#pragma unroll
  for (int l = 0; l < 8; l++) {
    const int row = l * 4 + (tid >> 6);
    const int kch = tid & 63;
    const int chg = (kch & 48) | ((kch ^ (row & 15)) & 15);  // involutive
    gl_lds16(x + (m0 + row) * 256 + chg * 4, &Xf[(l * 256 + tid) * 4]);
  }

  float bb[4];
#pragma unroll
  for (int e = 0; e < 4; e++) bb[e] = bias[(w * 4 + e) * 16 + c];

  f4 acc[2][4];
  const f4 z = {0.f, 0.f, 0.f, 0.f};
#pragma unroll
  for (int i = 0; i < 2; i++)
#pragma unroll
    for (int j = 0; j < 4; j++) acc[i][j] = z;

  __asm__ __volatile__("s_waitcnt vmcnt(0)\ns_barrier" ::: "memory");

  const short* wpb = Wp + (which * 4 + w) * 4 * 8 * 512;
#pragma unroll
  for (int ks = 0; ks < 8; ks++) {
    bf8 a[2], b[4];
#pragma unroll
    for (int ms = 0; ms < 2; ms++) {  // A[m=lane&15][k=quad*8+j]
      const int m = ms * 16 + c;
      const int ch0 = ks * 8 + quad * 2;
      const int sw0 = (ch0 & 48) | ((ch0 ^ c) & 15);
      const int sw1 = ((ch0 + 1) & 48) | (((ch0 + 1) ^ c) & 15);
      f4 f0 = *(const f4*)&Xf[m * 256 + sw0 * 4];
      f4 f1 = *(const f4*)&Xf[m * 256 + sw1 * 4];
      a[ms] = cvt8(f0, f1);
    }
#pragma unroll
    for (int e = 0; e < 4; e++)
      b[e] = *(const bf8*)(wpb + (e * 8 + ks) * 512 + lane * 8);
#pragma unroll
    for (int ms = 0; ms < 2; ms++)
#pragma unroll
      for (int e = 0; e < 4; e++) acc[ms][e] = mfma16(a[ms], b[e], acc[ms][e]);
  }

  const float sc = (which == 0) ? 0.09016844005556021f : 1.0f;  // log2e/16

  if (which < 2) {
    short* dst = (which == 0) ? Qs : Kb;
#pragma unroll
    for (int ms = 0; ms < 2; ms++)
#pragma unroll
      for (int e = 0; e < 4; e++)
#pragma unroll
        for (int r = 0; r < 4; r++)  // C/D: col=lane&15, row=quad*4+reg
          dst[(m0 + ms * 16 + quad * 4 + r) * 256 + (w * 4 + e) * 16 + c] =
              f2bf((acc[ms][e][r] + bb[e]) * sc);
  } else {
#pragma unroll
    for (int ms = 0; ms < 2; ms++)
#pragma unroll
      for (int e = 0; e < 4; e++)
#pragma unroll
        for (int r = 0; r < 4; r++)
          Vlds[((w * 4 + e) * 16 + c) * 36 + ms * 16 + quad * 4 + r] =
              f2bf(acc[ms][e][r] + bb[e]);
    __syncthreads();
    const int tt = m0 >> 6, half = m0 & 32;
#pragma unroll
    for (int j = 0; j < 4; j++) {
      int flat = j * 2048 + tid * 8;        // 256 d x 32 n
      int d = flat >> 5, n = flat & 31;
      *(bf8*)(Vt + tt * 16384 + d * 64 + half + n) =
          *(const bf8*)&Vlds[d * 36 + n];
    }
  }
}

// ---------------- kernel 2: flash attention ----------------
// 512 WGs (2/CU). batch = bx&3. Steady-state tile u (manual 2-phase):
//  issue V(u) asm -> stage K(u+1) gl_lds (dbuf) -> vmcnt(24) order-tie ->
//  QK from Klds[u&1] -> P=exp2(masked S) (mask from reg-dbuf) -> B2
//  (lgkm0+barrier) -> issue M(u+2) asm -> vmcnt(16) [V ready; retires
//  M(u+1) by FIFO] -> PV -> B1 (vmcnt(8)+barrier) [K(u+1) landed].
// No compiler VM ops anywhere in the loop.
__launch_bounds__(256, 2)
__global__ void flash(const short* __restrict__ Qs, const short* __restrict__ Kb,
                      const short* __restrict__ Vt, const int* __restrict__ mask,
                      float* __restrict__ out) {
  __shared__ short Klds[2][16384];    // K dbuf 64x256 x2, swizzled, 64KB
  __shared__ short Plds[2][32 * 76];  // P dbuf, stride 76 (conflict-free)
  const int bx = blockIdx.x;
  const int batch = bx & 3;
  const int q0 = (bx >> 2) * 32;
  const int tid = threadIdx.x;
  const int w = tid >> 6, lane = tid & 63, quad = lane >> 4, c = lane & 15;

  const short* kb = Kb + batch * 4096 * 256;
  const short* vb = Vt + batch * 1048576;
  const int* mb = mask + batch * 16777216;

  const int krow = tid >> 5;  // K staging: row-in-8-row-line (0..7)
  const int kch = tid & 31;   // LDS chunk this thread fills

  // ---- prologue: K(0)->Klds[0], M(0)->mA, M(1)->mB, Q via asm ----
#pragma unroll
  for (int l = 0; l < 8; l++) {
    const int row = l * 8 + krow;
    const int chg = (kch & 16) | ((kch ^ row) & 15);  // involutive swizzle
    gl_lds16(kb + row * 256 + chg * 8, &Klds[0][l * 2048 + tid * 8]);
  }
  int mA[8], mB[8];
#pragma unroll
  for (int ms = 0; ms < 2; ms++)
#pragma unroll
    for (int r = 0; r < 4; r++) {
      ld4(mA[ms * 4 + r], mb + (q0 + ms * 16 + quad * 4 + r) * 4096 + w * 16 + c);
      ld4(mB[ms * 4 + r],
          mb + (q0 + ms * 16 + quad * 4 + r) * 4096 + 64 + w * 16 + c);
    }
  bf8 aq[2][8];
  const short* qb = Qs + (batch * 4096 + q0) * 256;
#pragma unroll
  for (int ms = 0; ms < 2; ms++)
#pragma unroll
    for (int ks = 0; ks < 8; ks++)
      ld16(aq[ms][ks], qb + (ms * 16 + c) * 256 + ks * 32 + quad * 8);

  const f4 z = {0.f, 0.f, 0.f, 0.f};
  f4 accO[2][4], lacc[2];
#pragma unroll
  for (int ms = 0; ms < 2; ms++) {
    lacc[ms] = z;
#pragma unroll
    for (int ds = 0; ds < 4; ds++) accO[ms][ds] = z;
  }
  const bf8 ONES = {0x3F80, 0x3F80, 0x3F80, 0x3F80, 0x3F80, 0x3F80, 0x3F80, 0x3F80};

  // drain prologue; tie aq (16) + mA (8) = 24 operands
  __asm__ __volatile__("s_waitcnt vmcnt(0)\ns_barrier"
      : "+v"(aq[0][0]), "+v"(aq[0][1]), "+v"(aq[0][2]), "+v"(aq[0][3]),
        "+v"(aq[0][4]), "+v"(aq[0][5]), "+v"(aq[0][6]), "+v"(aq[0][7]),
        "+v"(aq[1][0]), "+v"(aq[1][1]), "+v"(aq[1][2]), "+v"(aq[1][3]),
        "+v"(aq[1][4]), "+v"(aq[1][5]), "+v"(aq[1][6]), "+v"(aq[1][7]),
        "+v"(mA[0]), "+v"(mA[1]), "+v"(mA[2]), "+v"(mA[3]),
        "+v"(mA[4]), "+v"(mA[5]), "+v"(mA[6]), "+v"(mA[7]) :: "memory");

  auto tile = [&](int t, short* krd, short* kst, int* mcur) {
    // ---- issue V(t) (asm regs) ----
    bf8 vc[2][4];
#pragma unroll
    for (int k2 = 0; k2 < 2; k2++)
#pragma unroll
      for (int ds = 0; ds < 4; ds++)
        ld16(vc[k2][ds], vb + t * 16384 + (w * 64 + ds * 16 + c) * 64 +
                         k2 * 32 + quad * 8);
    // ---- stage K(t+1) into the other buffer (read last at t-1) ----
    const int tk = (t < 63) ? t + 1 : 63;
    const short* kbt = kb + tk * 16384;
#pragma unroll
    for (int l = 0; l < 8; l++) {
      const int row = l * 8 + krow;
      const int chg = (kch & 16) | ((kch ^ row) & 15);
      gl_lds16(kbt + row * 256 + chg * 8, kst + l * 2048 + tid * 8);
    }
    // order-only fence: mask regs may only be read past this point
    // (outstanding here = leftover M(t+1):<=8 + V:8 + K:8 = <=24, no stall)
    __asm__ __volatile__("s_waitcnt vmcnt(24)"
        : "+v"(mA[0]), "+v"(mA[1]), "+v"(mA[2]), "+v"(mA[3]),
          "+v"(mA[4]), "+v"(mA[5]), "+v"(mA[6]), "+v"(mA[7]),
          "+v"(mB[0]), "+v"(mB[1]), "+v"(mB[2]), "+v"(mB[3]),
          "+v"(mB[4]), "+v"(mB[5]), "+v"(mB[6]), "+v"(mB[7]) :: "memory");

    // ---- S = Q' K^T from swizzled Klds[t&1] ----
    f4 s[2];
#pragma unroll
    for (int ms = 0; ms < 2; ms++) s[ms] = z;
#pragma unroll
    for (int ks = 0; ks < 8; ks++) {
      const int ch = ks * 4 + quad;
      const int sw = (ch & 16) | ((ch ^ c) & 15);
      const bf8 kf = *(const bf8*)&krd[(w * 16 + c) * 256 + sw * 8];
#pragma unroll
      for (int ms = 0; ms < 2; ms++) s[ms] = mfma16(aq[ms][ks], kf, s[ms]);
    }

    // ---- P = exp2(masked S) -> Plds[t&1] ----
    short* pw = &Plds[t & 1][0];
#pragma unroll
    for (int ms = 0; ms < 2; ms++)
#pragma unroll
      for (int r = 0; r < 4; r++) {
        float sv = (mcur[ms * 4 + r] != 0) ? s[ms][r] : -INFINITY;
        pw[(ms * 16 + quad * 4 + r) * 76 + w * 16 + c] =
            f2bf(__builtin_amdgcn_exp2f(sv));
      }
    // B2: P visible; VM queue untouched
    __asm__ __volatile__("s_waitcnt lgkmcnt(0)\ns_barrier" ::: "memory");

    // ---- issue M(t+2) into mcur (reads above are done; reg WAR orders) ----
    const int tm = (t + 2 < 64) ? t + 2 : 63;
#pragma unroll
    for (int ms = 0; ms < 2; ms++)
#pragma unroll
      for (int r = 0; r < 4; r++)
        ld4(mcur[ms * 4 + r],
            mb + (q0 + ms * 16 + quad * 4 + r) * 4096 + tm * 64 + w * 16 + c);

    // ---- V(t) ready; FIFO also retires M(t+1). Leaves K(t+1)+M(t+2). ----
    __asm__ __volatile__("s_waitcnt vmcnt(16)"
        : "+v"(vc[0][0]), "+v"(vc[0][1]), "+v"(vc[0][2]), "+v"(vc[0][3]),
          "+v"(vc[1][0]), "+v"(vc[1][1]), "+v"(vc[1][2]), "+v"(vc[1][3]),
          "+v"(mA[0]), "+v"(mA[1]), "+v"(mA[2]), "+v"(mA[3]),
          "+v"(mA[4]), "+v"(mA[5]), "+v"(mA[6]), "+v"(mA[7]),
          "+v"(mB[0]), "+v"(mB[1]), "+v"(mB[2]), "+v"(mB[3]),
          "+v"(mB[4]), "+v"(mB[5]), "+v"(mB[6]), "+v"(mB[7]) :: "memory");

    // ---- O += P V ; row-sum via ones-frag MFMA ----
#pragma unroll
    for (int k2 = 0; k2 < 2; k2++) {
      bf8 ap[2];
#pragma unroll
      for (int ms = 0; ms < 2; ms++)  // A[m=lane&15][k=quad*8+j]
        ap[ms] = *(const bf8*)&pw[(ms * 16 + c) * 76 + k2 * 32 + quad * 8];
#pragma unroll
      for (int ms = 0; ms < 2; ms++) {
        lacc[ms] = mfma16(ap[ms], ONES, lacc[ms]);
#pragma unroll
        for (int ds = 0; ds < 4; ds++)
          accO[ms][ds] = mfma16(ap[ms], vc[k2][ds], accO[ms][ds]);
      }
    }
    // B1: K(t+1) landed in LDS (issued ~1 tile ago); M(t+2) keeps flying
    __asm__ __volatile__("s_waitcnt vmcnt(8)\ns_barrier" ::: "memory");
  };

  for (int th = 0; th < 32; th++) {
    tile(2 * th, &Klds[0][0], &Klds[1][0], mA);
    tile(2 * th + 1, &Klds[1][0], &Klds[0][0], mB);
  }

  // ---- epilogue: O / l ----
  float* ob = out + (batch * 4096 + q0) * 256;
#pragma unroll
  for (int ms = 0; ms < 2; ms++) {
    f4 rl;
#pragma unroll
    for (int r = 0; r < 4; r++) rl[r] = __builtin_amdgcn_rcpf(lacc[ms][r]);
#pragma unroll
    for (int ds = 0; ds < 4; ds++)
#pragma unroll
      for (int r = 0; r < 4; r++)
        ob[(ms * 16 + quad * 4 + r) * 256 + w * 64 + ds * 16 + c] =
            accO[ms][ds][r] * rl[r];
  }
}

extern "C" void kernel_launch(void* const* d_in, const int* in_sizes, int n_in,
                              void* d_out, int out_size, void* d_ws, size_t ws_size,
                              hipStream_t stream) {
  const float* x = (const float*)d_in[0];
  const int* mask = (const int*)d_in[1];
  const float* Wq = (const float*)d_in[2];
  const float* bq = (const float*)d_in[3];
  const float* Wk = (const float*)d_in[4];
  const float* bk = (const float*)d_in[5];
  const float* Wv = (const float*)d_in[6];
  const float* bv = (const float*)d_in[7];
  float* out = (float*)d_out;

  char* ws = (char*)d_ws;  // 24 MiB + 384 KiB
  short* Qs = (short*)ws;
  short* Kb = (short*)(ws + (8u << 20));
  short* Vt = (short*)(ws + (16u << 20));
  short* Wp = (short*)(ws + (24u << 20));

  pack<<<96, 256, 0, stream>>>(Wq, Wk, Wv, Wp);
  qkv<<<dim3(512, 3), 256, 0, stream>>>(x, Wp, bq, bk, bv, Qs, Kb, Vt);
  flash<<<512, 256, 0, stream>>>(Qs, Kb, Vt, mask, out);
}